// Round 1
// baseline (80.150 us; speedup 1.0000x reference)
//
#include <hip/hip_runtime.h>
#include <hip/hip_bf16.h>

// Geometry
#define NW 64          // N*W = 4*16
#define P 128          // rows per (n,w)
#define D 96           // channels
#define GCH 101
#define SIM 100
#define LCH 80

// ws layout (float offsets)
#define WS_SCALE 0                     // 128 floats
#define WS_Q     128                   // 64*128*96
#define WS_KT    (128 + 786432)        // 64*96*128 (transposed: [c][r])
#define WS_VO    (128 + 2*786432)      // 64*128*96
#define WS_S     (128 + 3*786432)      // 64*128*128
#define WS_T     (128 + 3*786432 + 1048576) // 64*128*128

// K1: scale[g] = sigmoid(w_up[g,:]·mb + b_up[g]), g<101
__global__ void scale_kernel(const float* __restrict__ mb,
                             const float* __restrict__ w_up,
                             const float* __restrict__ b_up,
                             float* __restrict__ ws) {
  int g = threadIdx.x;
  if (g < GCH) {
    float acc = b_up[g];
    for (int j = 0; j < LCH; ++j) acc += w_up[g * LCH + j] * mb[j];
    ws[WS_SCALE + g] = 1.0f / (1.0f + __expf(-acc));
  }
}

// K2: per (nw, proj): OUT[128][96] = vq @ W^T (+scale0/bias for Q)
//   pj=0 -> Q (scale0*acc + b_q), pj=1 -> VKt transposed [c][r], pj=2 -> VO
__global__ __launch_bounds__(256) void proj_kernel(const float* __restrict__ v,
                                                   const float* __restrict__ wq,
                                                   const float* __restrict__ bq,
                                                   const float* __restrict__ wk,
                                                   const float* __restrict__ wo,
                                                   float* __restrict__ ws) {
  int nw = blockIdx.x / 3;
  int pj = blockIdx.x % 3;
  const float* W = (pj == 0) ? wq : (pj == 1) ? wk : wo;
  __shared__ float sWt[96 * 100];   // Wt[d][c], padded stride 100
  __shared__ float sV[64 * 100];    // half of vq rows, padded
  int tid = threadIdx.x;
  for (int idx = tid; idx < 96 * 96; idx += 256) {
    int c = idx / 96, d = idx - c * 96;
    sWt[d * 100 + c] = W[idx];
  }
  float scale0 = (pj == 0) ? ws[WS_SCALE + 0] : 0.0f;
  const float* vq = v + nw * (P * D);
  float* outQ  = ws + WS_Q  + nw * (P * D);
  float* outKt = ws + WS_KT + nw * (P * D);
  float* outO  = ws + WS_VO + nw * (P * D);
  int ty = tid >> 3;  // 0..31
  int tx = tid & 7;   // 0..7
  for (int half = 0; half < 2; ++half) {
    __syncthreads();
    for (int idx = tid; idx < 64 * 96; idx += 256) {
      int r = idx / 96, d = idx - r * 96;
      sV[r * 100 + d] = vq[half * (64 * 96) + idx];
    }
    __syncthreads();
    float acc0[12], acc1[12];
#pragma unroll
    for (int j = 0; j < 12; ++j) { acc0[j] = 0.f; acc1[j] = 0.f; }
    for (int d = 0; d < 96; ++d) {
      float v0 = sV[(ty * 2 + 0) * 100 + d];
      float v1 = sV[(ty * 2 + 1) * 100 + d];
#pragma unroll
      for (int j = 0; j < 12; ++j) {
        float w = sWt[d * 100 + tx * 12 + j];
        acc0[j] += v0 * w;
        acc1[j] += v1 * w;
      }
    }
    int r0 = half * 64 + ty * 2;
#pragma unroll
    for (int a = 0; a < 2; ++a) {
      int r = r0 + a;
      const float* accp = a ? acc1 : acc0;
#pragma unroll
      for (int j = 0; j < 12; ++j) {
        int c = tx * 12 + j;
        float val = accp[j];
        if (pj == 0)      outQ[r * 96 + c] = scale0 * val + bq[c];
        else if (pj == 1) outKt[c * P + r] = val;
        else              outO[r * 96 + c] = val;
      }
    }
  }
}

// K3: per (nw, ptile of 32): S[p][r] = sum_c Q[p][c] * VK[r][c]
__global__ __launch_bounds__(256) void smat_kernel(float* __restrict__ ws) {
  int nw = blockIdx.x >> 2;
  int pt = blockIdx.x & 3;
  __shared__ float sKt[96 * 128];  // [c][r]  48KB
  __shared__ float sQ[32 * 96];    // 12KB
  int tid = threadIdx.x;
  const float* kt = ws + WS_KT + nw * (P * D);
  const float* qq = ws + WS_Q + nw * (P * D) + pt * 32 * 96;
  for (int idx = tid; idx < 96 * 128; idx += 256) sKt[idx] = kt[idx];
  for (int idx = tid; idx < 32 * 96; idx += 256) sQ[idx] = qq[idx];
  __syncthreads();
  int pp = tid >> 4;  // 0..15
  int rr = tid & 15;  // 0..15
  float acc0[8] = {0,0,0,0,0,0,0,0};
  float acc1[8] = {0,0,0,0,0,0,0,0};
  for (int c = 0; c < 96; ++c) {
    float q0 = sQ[(pp * 2 + 0) * 96 + c];
    float q1 = sQ[(pp * 2 + 1) * 96 + c];
    const float* kd = &sKt[c * 128 + rr * 8];
#pragma unroll
    for (int j = 0; j < 8; ++j) {
      float k = kd[j];
      acc0[j] += q0 * k;
      acc1[j] += q1 * k;
    }
  }
  float* Sout = ws + WS_S + nw * (P * P) + pt * 32 * P;
#pragma unroll
  for (int j = 0; j < 8; ++j) Sout[(pp * 2 + 0) * P + rr * 8 + j] = acc0[j];
#pragma unroll
  for (int j = 0; j < 8; ++j) Sout[(pp * 2 + 1) * P + rr * 8 + j] = acc1[j];
}

// K4a: per (nw,p) row: rank -> keep top-100 -> position -> softmax -> t weights
__global__ __launch_bounds__(128) void tmat_kernel(const float* __restrict__ attn,
                                                   float* __restrict__ ws) {
  int bid = blockIdx.x;  // nw*128 + p
  __shared__ float sA[128];
  __shared__ int sW0;
  __shared__ float sMx[2];
  __shared__ float sSm[2];
  int tid = threadIdx.x;
  int wave = tid >> 6, lane = tid & 63;
  float a = attn[(size_t)bid * 128 + tid];
  sA[tid] = a;
  __syncthreads();
  int cnt = 0;
  for (int j = 0; j < 128; ++j) {
    float aj = sA[j];
    cnt += (aj > a) || (aj == a && j < tid);
  }
  bool keep = cnt < SIM;
  unsigned long long m = __ballot(keep);
  if (tid == 0) sW0 = 0;
  __syncthreads();
  if (wave == 0 && lane == 0) sW0 = __popcll(m);
  __syncthreads();
  int pos = __popcll(m & ((1ull << lane) - 1ull)) + (wave ? sW0 : 0);
  float sval = 0.f, sc = -1e30f;
  if (keep) {
    sval = ws[WS_SCALE + 1 + pos];
    sc = sval * ws[WS_S + (size_t)bid * 128 + tid] * 0.10206207261596577f; // 1/sqrt(96)
  }
  float mx = sc;
#pragma unroll
  for (int off = 32; off > 0; off >>= 1) mx = fmaxf(mx, __shfl_xor(mx, off));
  if (lane == 0) sMx[wave] = mx;
  __syncthreads();
  mx = fmaxf(sMx[0], sMx[1]);
  float e = keep ? __expf(sc - mx) : 0.f;
  float sm = e;
#pragma unroll
  for (int off = 32; off > 0; off >>= 1) sm += __shfl_xor(sm, off);
  if (lane == 0) sSm[wave] = sm;
  __syncthreads();
  sm = sSm[0] + sSm[1];
  float t = keep ? (e / sm) * sval : 0.f;
  ws[WS_T + (size_t)bid * 128 + tid] = t;
}

// K4b: per (nw, ptile of 32): OUT[p][c] = sum_i T[p][i]*VO[i][c] + b_o[c]
__global__ __launch_bounds__(256) void out_kernel(const float* __restrict__ bo,
                                                  const float* __restrict__ ws,
                                                  float* __restrict__ out) {
  int nw = blockIdx.x >> 2;
  int pt = blockIdx.x & 3;
  __shared__ float sVO[128 * 96];  // 48KB
  __shared__ float sT[32 * 128];   // 16KB, XOR-swizzled
  int tid = threadIdx.x;
  const float* vo = ws + WS_VO + nw * (P * D);
  const float* T = ws + WS_T + nw * (P * P) + pt * 32 * P;
  for (int idx = tid; idx < 128 * 96; idx += 256) sVO[idx] = vo[idx];
  for (int idx = tid; idx < 32 * 128; idx += 256) {
    int p = idx >> 7, i = idx & 127;
    sT[p * 128 + (i ^ ((p & 7) << 2))] = T[idx];  // swizzle kills bank conflict
  }
  __syncthreads();
  int ty = tid >> 3;  // 0..31 -> row
  int tx = tid & 7;   // 0..7 -> col block
  float acc[12];
#pragma unroll
  for (int j = 0; j < 12; ++j) acc[j] = 0.f;
  int sw = (ty & 7) << 2;
  for (int i = 0; i < 128; ++i) {
    float t = sT[ty * 128 + (i ^ sw)];
#pragma unroll
    for (int j = 0; j < 12; ++j) acc[j] += t * sVO[i * 96 + tx * 12 + j];
  }
  int p = pt * 32 + ty;
  float* o = out + nw * (P * D) + p * 96 + tx * 12;
#pragma unroll
  for (int j = 0; j < 12; ++j) o[j] = acc[j] + bo[tx * 12 + j];
}

extern "C" void kernel_launch(void* const* d_in, const int* in_sizes, int n_in,
                              void* d_out, int out_size, void* d_ws, size_t ws_size,
                              hipStream_t stream) {
  const float* attn = (const float*)d_in[0];
  const float* v    = (const float*)d_in[1];
  const float* mb   = (const float*)d_in[2];
  // d_in[3]=w_sub, d_in[4]=b_sub: dead code (softmax over singleton axis == 1)
  const float* w_up = (const float*)d_in[5];
  const float* b_up = (const float*)d_in[6];
  const float* w_q  = (const float*)d_in[7];
  const float* b_q  = (const float*)d_in[8];
  const float* w_k  = (const float*)d_in[9];
  // d_in[10]=b_k: drops out of softmax (constant shift per row), unused in out
  const float* w_o  = (const float*)d_in[11];
  const float* b_o  = (const float*)d_in[12];
  float* out = (float*)d_out;
  float* ws = (float*)d_ws;

  hipLaunchKernelGGL(scale_kernel, dim3(1), dim3(128), 0, stream, mb, w_up, b_up, ws);
  hipLaunchKernelGGL(proj_kernel, dim3(NW * 3), dim3(256), 0, stream, v, w_q, b_q, w_k, w_o, ws);
  hipLaunchKernelGGL(smat_kernel, dim3(NW * 4), dim3(256), 0, stream, ws);
  hipLaunchKernelGGL(tmat_kernel, dim3(NW * P), dim3(128), 0, stream, attn, ws);
  hipLaunchKernelGGL(out_kernel, dim3(NW * 4), dim3(256), 0, stream, b_o, ws, out);
}

// Round 2
// 56.201 us; speedup vs baseline: 1.4261x; 1.4261x over previous
//
#include <hip/hip_runtime.h>
#include <hip/hip_bf16.h>

// Geometry
#define NW 64          // N*W = 4*16
#define P 128          // rows per (n,w)
#define D 96           // channels
#define GCH 101
#define SIM 100
#define LCH 80
#define RSQRT96 0.10206207261596577f   // 1/sqrt(96)

// ws layout (float offsets)
#define WS_SCALE 0                     // 128 floats
#define WS_Q     128                   // 64*128*96
#define WS_KT    (128 + 786432)        // 64*96*128 (transposed: [c][r])
#define WS_VO    (128 + 2*786432)      // 64*128*96

// K1: per (nw, proj, half-of-rows): OUT[64][96] = vq @ W^T
//   pj=0 -> Q (scale0*acc + b_q), pj=1 -> K transposed [c][r], pj=2 -> VO
// Block 0 additionally writes the 101 sigmoid scale values to ws.
__global__ __launch_bounds__(256) void proj_kernel(const float* __restrict__ v,
    const float* __restrict__ wq, const float* __restrict__ bq,
    const float* __restrict__ wk, const float* __restrict__ wo,
    const float* __restrict__ mb, const float* __restrict__ w_up,
    const float* __restrict__ b_up, float* __restrict__ ws) {
  int bid = blockIdx.x;       // 0..383
  int nw = bid / 6;
  int rem = bid - nw * 6;
  int pj = rem >> 1;
  int half = rem & 1;
  const float* W = (pj == 0) ? wq : (pj == 1) ? wk : wo;
  __shared__ float sWt[96 * 100];   // Wt[d][c], stride 100 (400B, 16B-aligned)
  __shared__ float sV[64 * 100];
  int tid = threadIdx.x;
  for (int idx = tid; idx < 96 * 96; idx += 256) {
    int c = idx / 96, d = idx - c * 96;
    sWt[d * 100 + c] = W[idx];
  }
  float scale0 = 0.0f;
  if (pj == 0) {  // scale[0] = sigmoid(w_up[0,:]·mb + b_up[0]), uniform -> cheap
    float acc = b_up[0];
    for (int j = 0; j < LCH; ++j) acc += w_up[j] * mb[j];
    scale0 = 1.0f / (1.0f + __expf(-acc));
  }
  const float* vq = v + nw * (P * D) + half * (64 * D);
  for (int idx = tid; idx < 64 * 96; idx += 256) {
    int r = idx / 96, d = idx - r * 96;
    sV[r * 100 + d] = vq[idx];
  }
  __syncthreads();
  int ty = tid >> 3;  // 0..31 -> row pair
  int tx = tid & 7;   // 0..7  -> col block of 12
  float acc0[12], acc1[12];
#pragma unroll
  for (int j = 0; j < 12; ++j) { acc0[j] = 0.f; acc1[j] = 0.f; }
  for (int d = 0; d < 96; ++d) {
    float v0 = sV[(ty * 2 + 0) * 100 + d];
    float v1 = sV[(ty * 2 + 1) * 100 + d];
    const float4* wp = (const float4*)&sWt[d * 100 + tx * 12];  // 3x ds_read_b128
    float4 w0 = wp[0], w1 = wp[1], w2 = wp[2];
    float wbuf[12] = {w0.x,w0.y,w0.z,w0.w, w1.x,w1.y,w1.z,w1.w, w2.x,w2.y,w2.z,w2.w};
#pragma unroll
    for (int j = 0; j < 12; ++j) {
      acc0[j] += v0 * wbuf[j];
      acc1[j] += v1 * wbuf[j];
    }
  }
  float* outQ  = ws + WS_Q  + nw * (P * D);
  float* outKt = ws + WS_KT + nw * (P * D);
  float* outO  = ws + WS_VO + nw * (P * D);
  int r0 = half * 64 + ty * 2;
#pragma unroll
  for (int a = 0; a < 2; ++a) {
    int r = r0 + a;
    const float* accp = a ? acc1 : acc0;
#pragma unroll
    for (int j = 0; j < 12; ++j) {
      int c = tx * 12 + j;
      float val = accp[j];
      if (pj == 0)      outQ[r * 96 + c] = scale0 * val + bq[c];
      else if (pj == 1) outKt[c * P + r] = val;
      else              outO[r * 96 + c] = val;
    }
  }
  // full scale vector (written once; consumed by next kernel in stream order)
  if (bid == 0 && tid < GCH) {
    float acc = b_up[tid];
    for (int j = 0; j < LCH; ++j) acc += w_up[tid * LCH + j] * mb[j];
    ws[WS_SCALE + tid] = 1.0f / (1.0f + __expf(-acc));
  }
}

// K2: fused attention per (nw, 4-row tile): S = q·k, top-100 rank (exact
// tie semantics via u64 keys), softmax, out = T @ VO + b_o.
__global__ __launch_bounds__(128) void attn_kernel(const float* __restrict__ attn,
    const float* __restrict__ bo, const float* __restrict__ ws,
    float* __restrict__ out) {
  int bid = blockIdx.x;       // 0..2047
  int nw = bid >> 5;
  int pt = bid & 31;
  int p0 = pt * 4;
  int tid = threadIdx.x;      // 0..127 = key/column index
  int wave = tid >> 6, lane = tid & 63;
  __shared__ float sQ[4 * 96];
  __shared__ unsigned long long sKey[4 * 128];
  __shared__ float sT[4 * 128];
  __shared__ float sScale[104];
  __shared__ unsigned long long sB[4];
  __shared__ float sMx[4][2];
  __shared__ float sSm[4][2];
  const float* Qg = ws + WS_Q  + nw * (P * D);
  const float* Kt = ws + WS_KT + nw * (P * D);
  const float* VO = ws + WS_VO + nw * (P * D);
  if (tid < GCH) sScale[tid] = ws[WS_SCALE + tid];
  for (int idx = tid; idx < 4 * 96; idx += 128) sQ[idx] = Qg[p0 * 96 + idx];
  unsigned long long mykey[4];
#pragma unroll
  for (int r = 0; r < 4; ++r) {
    float a = attn[((size_t)(nw * 128 + p0 + r)) * 128 + tid];
    unsigned u = __float_as_uint(a);
    unsigned msk = (u & 0x80000000u) ? 0xFFFFFFFFu : 0x80000000u;
    unsigned long long k =
        (((unsigned long long)(u ^ msk)) << 32) | (unsigned)(127 - tid);
    mykey[r] = k;
    sKey[r * 128 + tid] = k;
  }
  __syncthreads();
  // S[r][tid] = q_r · k_tid  (Kt stream is coalesced; sQ reads broadcast)
  float acc[4] = {0.f, 0.f, 0.f, 0.f};
  for (int c = 0; c < 96; ++c) {
    float kv = Kt[c * P + tid];
#pragma unroll
    for (int r = 0; r < 4; ++r) acc[r] += sQ[r * 96 + c] * kv;
  }
  // exact rank: count elements strictly greater under (value desc, index asc)
  int cnt[4] = {0, 0, 0, 0};
#pragma unroll 4
  for (int j = 0; j < 128; ++j) {
#pragma unroll
    for (int r = 0; r < 4; ++r)
      cnt[r] += (sKey[r * 128 + j] > mykey[r]) ? 1 : 0;
  }
  bool keep[4];
  unsigned long long bal[4];
#pragma unroll
  for (int r = 0; r < 4; ++r) {
    keep[r] = cnt[r] < SIM;
    bal[r] = __ballot(keep[r]);
  }
  if (wave == 0 && lane == 0) {
#pragma unroll
    for (int r = 0; r < 4; ++r) sB[r] = bal[r];
  }
  __syncthreads();
  float sval[4], sc[4], mx[4];
#pragma unroll
  for (int r = 0; r < 4; ++r) {
    int pos = __popcll(bal[r] & ((1ull << lane) - 1ull)) +
              (wave ? __popcll(sB[r]) : 0);
    sval[r] = keep[r] ? sScale[1 + pos] : 0.f;
    sc[r] = keep[r] ? sval[r] * acc[r] * RSQRT96 : -1e30f;
    mx[r] = sc[r];
#pragma unroll
    for (int off = 32; off > 0; off >>= 1) mx[r] = fmaxf(mx[r], __shfl_xor(mx[r], off));
    if (lane == 0) sMx[r][wave] = mx[r];
  }
  __syncthreads();
  float e[4], sm[4];
#pragma unroll
  for (int r = 0; r < 4; ++r) {
    float M = fmaxf(sMx[r][0], sMx[r][1]);
    e[r] = keep[r] ? __expf(sc[r] - M) : 0.f;
    sm[r] = e[r];
#pragma unroll
    for (int off = 32; off > 0; off >>= 1) sm[r] += __shfl_xor(sm[r], off);
    if (lane == 0) sSm[r][wave] = sm[r];
  }
  __syncthreads();
#pragma unroll
  for (int r = 0; r < 4; ++r) {
    float S = sSm[r][0] + sSm[r][1];
    sT[r * 128 + tid] = keep[r] ? (e[r] / S) * sval[r] : 0.f;
  }
  __syncthreads();
  // out[r][c] = sum_j T[r][j] * VO[j][c] + b_o[c]
  if (tid < D) {
    float facc[4] = {0.f, 0.f, 0.f, 0.f};
    for (int j = 0; j < 128; ++j) {
      float vo = VO[j * D + tid];
#pragma unroll
      for (int r = 0; r < 4; ++r) facc[r] += sT[r * 128 + j] * vo;
    }
    float bb = bo[tid];
#pragma unroll
    for (int r = 0; r < 4; ++r)
      out[((size_t)(nw * 128 + p0 + r)) * D + tid] = facc[r] + bb;
  }
}

extern "C" void kernel_launch(void* const* d_in, const int* in_sizes, int n_in,
                              void* d_out, int out_size, void* d_ws, size_t ws_size,
                              hipStream_t stream) {
  const float* attn = (const float*)d_in[0];
  const float* v    = (const float*)d_in[1];
  const float* mb   = (const float*)d_in[2];
  // d_in[3]=w_sub, d_in[4]=b_sub: dead (softmax over singleton axis == 1)
  const float* w_up = (const float*)d_in[5];
  const float* b_up = (const float*)d_in[6];
  const float* w_q  = (const float*)d_in[7];
  const float* b_q  = (const float*)d_in[8];
  const float* w_k  = (const float*)d_in[9];
  // d_in[10]=b_k: constant shift per row -> drops out of softmax, unused
  const float* w_o  = (const float*)d_in[11];
  const float* b_o  = (const float*)d_in[12];
  float* out = (float*)d_out;
  float* ws = (float*)d_ws;

  hipLaunchKernelGGL(proj_kernel, dim3(NW * 6), dim3(256), 0, stream,
                     v, w_q, b_q, w_k, w_o, mb, w_up, b_up, ws);
  hipLaunchKernelGGL(attn_kernel, dim3(NW * 32), dim3(128), 0, stream,
                     attn, b_o, ws, out);
}